// Round 17
// baseline (386.497 us; speedup 1.0000x reference)
//
#include <hip/hip_runtime.h>

#define NB 8
#define NQ 2048
#define NK 2048
#define ND 512
#define QB 64
#define KB 512
#define MASK_VALUE (-1e-06f)
#define PLANE  ((size_t)NB * NK * ND)
#define WPLANE ((size_t)ND * ND)

typedef __attribute__((ext_vector_type(4))) float f32x4;
typedef __attribute__((ext_vector_type(8))) __bf16 bf16x8;
typedef __attribute__((ext_vector_type(8))) _Float16 f16x8;
typedef __attribute__((ext_vector_type(4))) _Float16 f16x4;
typedef __attribute__((ext_vector_type(8))) unsigned short u16x8;
typedef __attribute__((ext_vector_type(4))) unsigned int u32x4;

typedef f32x4  __attribute__((may_alias)) f32x4_ma;
typedef bf16x8 __attribute__((may_alias)) bf16x8_ma;
typedef f16x8  __attribute__((may_alias)) f16x8_ma;
typedef f16x4  __attribute__((may_alias)) f16x4_ma;
typedef u32x4  __attribute__((may_alias)) u32x4_ma;

__device__ __forceinline__ unsigned short f2bf(float x){
    union { float f; unsigned u; } v; v.f = x;
    unsigned r = v.u + 0x7fffu + ((v.u >> 16) & 1u);
    return (unsigned short)(r >> 16);
}
__device__ __forceinline__ float bf2f(unsigned short h){
    union { unsigned u; float f; } v; v.u = ((unsigned)h) << 16;
    return v.f;
}

// ---------------- prep 1: K -> SINGLE fp16 plane, layout [b][k][e] ----------------
__global__ __launch_bounds__(256)
void conv_k_f16_kernel(const float* __restrict__ K,
                       _Float16* __restrict__ kf)
{
    const size_t i = ((size_t)blockIdx.x * 256 + threadIdx.x) * 4;
    const f32x4 v = *(const f32x4_ma*)(K + i);
    f16x4 h;
    #pragma unroll
    for (int c = 0; c < 4; ++c) h[c] = (_Float16)v[c];
    *(f16x4_ma*)(kf + i) = h;
}

// -------- prep 2: V -> single fp16 plane TRANSPOSED, layout [b][d][k] --------
__global__ __launch_bounds__(256)
void transpose_v_f16_kernel(const float* __restrict__ V,
                            _Float16* __restrict__ vt)
{
    __shared__ float t[64][68];
    const int tid = threadIdx.x;
    const int bid = blockIdx.x;
    const int dt  = bid & 7;
    const int kt  = (bid >> 3) & 31;
    const int b   = bid >> 8;
    {
        const int rr = tid >> 4;
        const int c4 = (tid & 15) * 4;
        #pragma unroll
        for (int m4 = 0; m4 < 4; ++m4){
            const int kr = rr + m4*16;
            *(f32x4_ma*)&t[kr][c4] =
                *(const f32x4_ma*)&V[((size_t)b*NK + kt*64 + kr)*ND + dt*64 + c4];
        }
    }
    __syncthreads();
    {
        const int dr = tid >> 2;
        const int kc = (tid & 3) * 16;
        f16x8 v0, v1;
        #pragma unroll
        for (int j = 0; j < 8; ++j) v0[j] = (_Float16)t[kc + j][dr];
        #pragma unroll
        for (int j = 0; j < 8; ++j) v1[j] = (_Float16)t[kc + 8 + j][dr];
        const size_t dst = ((size_t)b*ND + dt*64 + dr)*NK + kt*64 + kc;
        *(f16x8_ma*)(vt + dst)     = v0;
        *(f16x8_ma*)(vt + dst + 8) = v1;
    }
}

// -------- prep 3: W -> hi/lo bf16 planes TRANSPOSED, layout [e][d] --------
__global__ __launch_bounds__(256)
void transpose_split_w_kernel(const float* __restrict__ W,
                              unsigned short* __restrict__ wth,
                              unsigned short* __restrict__ wtl)
{
    __shared__ float t[64][68];
    const int tid = threadIdx.x;
    const int et  = blockIdx.x & 7;
    const int dt  = blockIdx.x >> 3;
    {
        const int rr = tid >> 4;
        const int c4 = (tid & 15) * 4;
        #pragma unroll
        for (int m4 = 0; m4 < 4; ++m4){
            const int dr = rr + m4*16;
            *(f32x4_ma*)&t[dr][c4] =
                *(const f32x4_ma*)&W[(size_t)(dt*64 + dr)*ND + et*64 + c4];
        }
    }
    __syncthreads();
    {
        const int er = tid >> 2;
        const int dc = (tid & 3) * 16;
        unsigned short hh[16], ll[16];
        #pragma unroll
        for (int j = 0; j < 16; ++j){
            const float v = t[dc + j][er];
            const unsigned short h = f2bf(v);
            hh[j] = h;
            ll[j] = f2bf(v - bf2f(h));
        }
        u32x4 h0, h1, l0, l1;
        #pragma unroll
        for (int c = 0; c < 4; ++c){
            h0[c] = (unsigned)hh[2*c]   | ((unsigned)hh[2*c+1] << 16);
            h1[c] = (unsigned)hh[8+2*c] | ((unsigned)hh[9+2*c] << 16);
            l0[c] = (unsigned)ll[2*c]   | ((unsigned)ll[2*c+1] << 16);
            l1[c] = (unsigned)ll[8+2*c] | ((unsigned)ll[9+2*c] << 16);
        }
        const size_t dst = (size_t)(et*64 + er)*ND + dt*64 + dc;
        *(u32x4_ma*)(wth + dst)     = h0;
        *(u32x4_ma*)(wth + dst + 8) = h1;
        *(u32x4_ma*)(wtl + dst)     = l0;
        *(u32x4_ma*)(wtl + dst + 8) = l1;
    }
}

// ----- main fused kernel: wave reshaping (wk=wv&7 keys/d, wr=wv>>3 row-half) -----
// Halves LDS A-fragment reads (each reused 4x); denominator via register partials
// (no ones-MFMA); same MFMA count for QK/PV.
__global__ __launch_bounds__(1024, 4)
void attn_kernel(const float* __restrict__ Qp, const int* __restrict__ Mp,
                 const _Float16* __restrict__ Kf,
                 const _Float16* __restrict__ Vt,
                 const unsigned short* __restrict__ Wth, const unsigned short* __restrict__ Wtl,
                 float* __restrict__ Op)
{
    __shared__ _Float16 qw[QB][520];    // 66.6 KB
    __shared__ _Float16 p_b[QB][520];   // 66.6 KB
    __shared__ float wredA[QB][8];      // 2 KB -> 135 KB total, 1 block/CU

    const int tid  = threadIdx.x;
    const int lane = tid & 63;
    const int wv   = tid >> 6;              // wave 0..15
    const int wk   = wv & 7;                // key-group (QK) / d-group (PV)
    const int wr   = wv >> 3;               // row half (0: rows 0-31, 1: rows 32-63)
    const int rowbase = wr * 32;
    const int lm   = lane & 15;
    const int lg   = lane >> 4;
    const int b    = blockIdx.x & 7;        // batch -> XCD affinity
    const int q0   = (int)(blockIdx.x >> 3) * QB;

    int mk;
    {   // tolerate int64-encoded masks (values >=1, so odd words all-zero => int64)
        const int odd = Mp[1] | Mp[3] | Mp[5] | Mp[7];
        mk = (odd == 0) ? Mp[2*b] : Mp[b];
    }

    // ===== Phase 1: qw[64][512] = Q_tile @ W via bf16 hi/lo 3-term MFMA (unchanged) =====
    {
        f32x4 acc[4][2];
        #pragma unroll
        for (int m2 = 0; m2 < 4; ++m2)
            #pragma unroll
            for (int n2 = 0; n2 < 2; ++n2) acc[m2][n2] = (f32x4){0.f,0.f,0.f,0.f};

        for (int w = 0; w < 16; ++w){
            bf16x8 aH[4], aL[4];
            #pragma unroll
            for (int m2 = 0; m2 < 4; ++m2){
                const float* qp = Qp + ((size_t)b*NQ + q0 + m2*16 + lm)*ND + w*32 + lg*8;
                const f32x4 qa = *(const f32x4_ma*)qp;
                const f32x4 qb = *(const f32x4_ma*)(qp + 4);
                u16x8 hh, ll;
                #pragma unroll
                for (int c = 0; c < 4; ++c){
                    const unsigned short h = f2bf(qa[c]);
                    hh[c] = h; ll[c] = f2bf(qa[c] - bf2f(h));
                }
                #pragma unroll
                for (int c = 0; c < 4; ++c){
                    const unsigned short h = f2bf(qb[c]);
                    hh[4+c] = h; ll[4+c] = f2bf(qb[c] - bf2f(h));
                }
                aH[m2] = __builtin_bit_cast(bf16x8, hh);
                aL[m2] = __builtin_bit_cast(bf16x8, ll);
            }
            #pragma unroll
            for (int n2 = 0; n2 < 2; ++n2){
                const size_t wrow = (size_t)(wv*32 + n2*16 + lm)*ND + w*32 + lg*8;
                const bf16x8 bh = *(const bf16x8_ma*)(Wth + wrow);
                const bf16x8 bl = *(const bf16x8_ma*)(Wtl + wrow);
                #pragma unroll
                for (int m2 = 0; m2 < 4; ++m2){
                    acc[m2][n2] = __builtin_amdgcn_mfma_f32_16x16x32_bf16(aH[m2], bh, acc[m2][n2], 0,0,0);
                    acc[m2][n2] = __builtin_amdgcn_mfma_f32_16x16x32_bf16(aH[m2], bl, acc[m2][n2], 0,0,0);
                    acc[m2][n2] = __builtin_amdgcn_mfma_f32_16x16x32_bf16(aL[m2], bh, acc[m2][n2], 0,0,0);
                }
            }
        }
        #pragma unroll
        for (int m2 = 0; m2 < 4; ++m2)
            #pragma unroll
            for (int n2 = 0; n2 < 2; ++n2)
                #pragma unroll
                for (int r = 0; r < 4; ++r)
                    qw[m2*16 + lg*4 + r][wv*32 + n2*16 + lm] = (_Float16)acc[m2][n2][r];
    }
    __syncthreads();

    // ===== Phase 2: flash loop over 4 tiles of 512 keys =====
    float m_run[2][4], lsum[2][4];
    #pragma unroll
    for (int m2 = 0; m2 < 2; ++m2)
        #pragma unroll
        for (int r = 0; r < 4; ++r){ m_run[m2][r] = -3.0e38f; lsum[m2][r] = 0.f; }

    f32x4 o_acc[2][4];   // rows: rowbase + m2*16 + lg*4 + r; d: wk*64 + n*16 + lm
    #pragma unroll
    for (int m2 = 0; m2 < 2; ++m2)
        #pragma unroll
        for (int n = 0; n < 4; ++n) o_acc[m2][n] = (f32x4){0.f,0.f,0.f,0.f};

    // QK: wave covers keys {h*128 + wk*16 + lm, h=0..3} of each tile, rows rowbase..+31
    const _Float16* kfb = Kf + ((size_t)b*NK + wk*16 + lm)*ND;
    // PV: wave covers d in [wk*64, +64)
    const size_t vbase = ((size_t)b*ND + wk*64 + lm)*NK + lg*8;

    for (int kt = 0; kt < NK/KB; ++kt){
        const int k0 = kt * KB;
        const size_t koff = (size_t)k0 * ND;

        // ---- QK^T (fp16): aQ read once, reused for 4 key-chunks ----
        f32x4 sacc[4][2];   // [h][m2]
        #pragma unroll
        for (int h = 0; h < 4; ++h)
            #pragma unroll
            for (int m2 = 0; m2 < 2; ++m2) sacc[h][m2] = (f32x4){0.f,0.f,0.f,0.f};
        #pragma unroll
        for (int w = 0; w < 16; ++w){
            const int eoff = w*32 + lg*8;
            f16x8 bk[4];
            #pragma unroll
            for (int h = 0; h < 4; ++h)
                bk[h] = *(const f16x8_ma*)(kfb + koff + (size_t)h*128*ND + eoff);
            #pragma unroll
            for (int m2 = 0; m2 < 2; ++m2){
                const f16x8 aQ = *(const f16x8_ma*)&qw[rowbase + m2*16 + lm][eoff];
                #pragma unroll
                for (int h = 0; h < 4; ++h)
                    sacc[h][m2] = __builtin_amdgcn_mfma_f32_16x16x32_f16(aQ, bk[h], sacc[h][m2], 0,0,0);
            }
        }

        // ---- faithful mask (lane-local keys: k0 + h*128 + wk*16 + lm) ----
        float sv[4][2][4];
        #pragma unroll
        for (int h = 0; h < 4; ++h){
            const bool inval = (k0 + h*128 + wk*16 + lm) >= mk;
            #pragma unroll
            for (int m2 = 0; m2 < 2; ++m2)
                #pragma unroll
                for (int r = 0; r < 4; ++r)
                    sv[h][m2][r] = inval ? MASK_VALUE : sacc[h][m2][r];
        }

        // ---- per-wave row max over its 64 keys, publish ----
        float pm[2][4];
        #pragma unroll
        for (int m2 = 0; m2 < 2; ++m2)
            #pragma unroll
            for (int r = 0; r < 4; ++r)
                pm[m2][r] = fmaxf(fmaxf(sv[0][m2][r], sv[1][m2][r]),
                                  fmaxf(sv[2][m2][r], sv[3][m2][r]));
        #pragma unroll
        for (int off = 1; off < 16; off <<= 1)
            #pragma unroll
            for (int m2 = 0; m2 < 2; ++m2)
                #pragma unroll
                for (int r = 0; r < 4; ++r)
                    pm[m2][r] = fmaxf(pm[m2][r], __shfl_xor(pm[m2][r], off, 64));
        if (lm == 0){
            #pragma unroll
            for (int m2 = 0; m2 < 2; ++m2)
                #pragma unroll
                for (int r = 0; r < 4; ++r)
                    wredA[rowbase + m2*16 + lg*4 + r][wk] = pm[m2][r];
        }
        __syncthreads();

        // ---- mnew + exact defer-max rescale + p -> fp16 LDS + register denominator ----
        #pragma unroll
        for (int m2 = 0; m2 < 2; ++m2)
            #pragma unroll
            for (int r = 0; r < 4; ++r){
                const int row = rowbase + m2*16 + lg*4 + r;
                const f32x4 g0 = *(const f32x4_ma*)&wredA[row][0];
                const f32x4 g1 = *(const f32x4_ma*)&wredA[row][4];
                const float gm = fmaxf(fmaxf(fmaxf(g0[0],g0[1]),fmaxf(g0[2],g0[3])),
                                       fmaxf(fmaxf(g1[0],g1[1]),fmaxf(g1[2],g1[3])));
                if (gm > m_run[m2][r]){          // exact skip: fsc==1 when gm<=m_run
                    const float fsc = __expf(m_run[m2][r] - gm);
                    m_run[m2][r] = gm;
                    #pragma unroll
                    for (int n = 0; n < 4; ++n) o_acc[m2][n][r] *= fsc;
                    lsum[m2][r] *= fsc;
                }
                float ls = 0.f;
                #pragma unroll
                for (int h = 0; h < 4; ++h){
                    const _Float16 ph = (_Float16)__expf(sv[h][m2][r] - m_run[m2][r]);
                    p_b[row][h*128 + wk*16 + lm] = ph;
                    ls += (float)ph;             // same fp16-rounded p as PV numerator
                }
                lsum[m2][r] += ls;
            }
        __syncthreads();

        // ---- PV: pa read once, reused for 4 d-columns (no ones-MFMA) ----
        #pragma unroll
        for (int kb = 0; kb < 16; ++kb){
            f16x8 vv[4];
            #pragma unroll
            for (int n = 0; n < 4; ++n)
                vv[n] = *(const f16x8_ma*)(Vt + vbase + (size_t)n*16*NK + k0 + kb*32);
            f16x8 pa[2];
            #pragma unroll
            for (int m2 = 0; m2 < 2; ++m2)
                pa[m2] = *(const f16x8_ma*)&p_b[rowbase + m2*16 + lm][kb*32 + lg*8];
            #pragma unroll
            for (int m2 = 0; m2 < 2; ++m2)
                #pragma unroll
                for (int n = 0; n < 4; ++n)
                    o_acc[m2][n] = __builtin_amdgcn_mfma_f32_16x16x32_f16(pa[m2], vv[n], o_acc[m2][n], 0,0,0);
        }
    }

    // ===== epilogue: cross-lane + cross-wave denominator, normalize, store =====
    #pragma unroll
    for (int off = 1; off < 16; off <<= 1)
        #pragma unroll
        for (int m2 = 0; m2 < 2; ++m2)
            #pragma unroll
            for (int r = 0; r < 4; ++r)
                lsum[m2][r] += __shfl_xor(lsum[m2][r], off, 64);
    if (lm == 0){
        #pragma unroll
        for (int m2 = 0; m2 < 2; ++m2)
            #pragma unroll
            for (int r = 0; r < 4; ++r)
                wredA[rowbase + m2*16 + lg*4 + r][wk] = lsum[m2][r];
    }
    __syncthreads();
    #pragma unroll
    for (int m2 = 0; m2 < 2; ++m2){
        float li[4];
        #pragma unroll
        for (int r = 0; r < 4; ++r){
            const int row = rowbase + m2*16 + lg*4 + r;
            const f32x4 s0 = *(const f32x4_ma*)&wredA[row][0];
            const f32x4 s1 = *(const f32x4_ma*)&wredA[row][4];
            li[r] = 1.f / (((s0[0]+s0[1]) + (s0[2]+s0[3])) + ((s1[0]+s1[1]) + (s1[2]+s1[3])));
        }
        #pragma unroll
        for (int n = 0; n < 4; ++n)
            #pragma unroll
            for (int r = 0; r < 4; ++r)
                Op[((size_t)b*NQ + q0 + rowbase + m2*16 + lg*4 + r)*ND + wk*64 + n*16 + lm]
                    = o_acc[m2][n][r] * li[r];
    }
}

extern "C" void kernel_launch(void* const* d_in, const int* in_sizes, int n_in,
                              void* d_out, int out_size, void* d_ws, size_t ws_size,
                              hipStream_t stream)
{
    (void)in_sizes; (void)n_in; (void)out_size; (void)ws_size;
    const float* Qp = (const float*)d_in[0];
    const float* Kp = (const float*)d_in[1];
    const float* Vp = (const float*)d_in[2];
    const float* Wp = (const float*)d_in[3];
    const int*   Mp = (const int*)  d_in[4];
    float* Op = (float*)d_out;

    unsigned short* wsu = (unsigned short*)d_ws;   // 34.6 MB total
    _Float16*       Kf  = (_Float16*)wsu;
    _Float16*       Vt  = (_Float16*)(wsu + PLANE);
    unsigned short* Wth = wsu + 2*PLANE;
    unsigned short* Wtl = wsu + 2*PLANE + WPLANE;

    hipLaunchKernelGGL(conv_k_f16_kernel, dim3(PLANE/1024), dim3(256), 0, stream,
                       Kp, Kf);
    hipLaunchKernelGGL(transpose_v_f16_kernel, dim3(NB*32*8), dim3(256), 0, stream,
                       Vp, Vt);
    hipLaunchKernelGGL(transpose_split_w_kernel, dim3(64), dim3(256), 0, stream,
                       Wp, Wth, Wtl);
    hipLaunchKernelGGL(attn_kernel, dim3(NB*(NQ/QB)), dim3(1024), 0, stream,
                       Qp, Mp, Kf, Vt, Wth, Wtl, Op);
}

// Round 18
// 269.759 us; speedup vs baseline: 1.4327x; 1.4327x over previous
//
#include <hip/hip_runtime.h>

#define NB 8
#define NQ 2048
#define NK 2048
#define ND 512
#define QB 64
#define KB 512
#define MASK_VALUE (-1e-06f)
#define PLANE  ((size_t)NB * NK * ND)
#define WPLANE ((size_t)ND * ND)

typedef __attribute__((ext_vector_type(4))) float f32x4;
typedef __attribute__((ext_vector_type(8))) __bf16 bf16x8;
typedef __attribute__((ext_vector_type(8))) _Float16 f16x8;
typedef __attribute__((ext_vector_type(4))) _Float16 f16x4;
typedef __attribute__((ext_vector_type(8))) unsigned short u16x8;
typedef __attribute__((ext_vector_type(4))) unsigned int u32x4;

typedef f32x4  __attribute__((may_alias)) f32x4_ma;
typedef bf16x8 __attribute__((may_alias)) bf16x8_ma;
typedef f16x8  __attribute__((may_alias)) f16x8_ma;
typedef f16x4  __attribute__((may_alias)) f16x4_ma;
typedef u32x4  __attribute__((may_alias)) u32x4_ma;

__device__ __forceinline__ unsigned short f2bf(float x){
    union { float f; unsigned u; } v; v.f = x;
    unsigned r = v.u + 0x7fffu + ((v.u >> 16) & 1u);
    return (unsigned short)(r >> 16);
}
__device__ __forceinline__ float bf2f(unsigned short h){
    union { unsigned u; float f; } v; v.u = ((unsigned)h) << 16;
    return v.f;
}

// ---------------- prep 1: K -> SINGLE fp16 plane, layout [b][k][e] ----------------
__global__ __launch_bounds__(256)
void conv_k_f16_kernel(const float* __restrict__ K,
                       _Float16* __restrict__ kf)
{
    const size_t i = ((size_t)blockIdx.x * 256 + threadIdx.x) * 4;
    const f32x4 v = *(const f32x4_ma*)(K + i);
    f16x4 h;
    #pragma unroll
    for (int c = 0; c < 4; ++c) h[c] = (_Float16)v[c];
    *(f16x4_ma*)(kf + i) = h;
}

// -------- prep 2: V -> single fp16 plane TRANSPOSED, layout [b][d][k] --------
__global__ __launch_bounds__(256)
void transpose_v_f16_kernel(const float* __restrict__ V,
                            _Float16* __restrict__ vt)
{
    __shared__ float t[64][68];
    const int tid = threadIdx.x;
    const int bid = blockIdx.x;
    const int dt  = bid & 7;
    const int kt  = (bid >> 3) & 31;
    const int b   = bid >> 8;
    {
        const int rr = tid >> 4;
        const int c4 = (tid & 15) * 4;
        #pragma unroll
        for (int m4 = 0; m4 < 4; ++m4){
            const int kr = rr + m4*16;
            *(f32x4_ma*)&t[kr][c4] =
                *(const f32x4_ma*)&V[((size_t)b*NK + kt*64 + kr)*ND + dt*64 + c4];
        }
    }
    __syncthreads();
    {
        const int dr = tid >> 2;
        const int kc = (tid & 3) * 16;
        f16x8 v0, v1;
        #pragma unroll
        for (int j = 0; j < 8; ++j) v0[j] = (_Float16)t[kc + j][dr];
        #pragma unroll
        for (int j = 0; j < 8; ++j) v1[j] = (_Float16)t[kc + 8 + j][dr];
        const size_t dst = ((size_t)b*ND + dt*64 + dr)*NK + kt*64 + kc;
        *(f16x8_ma*)(vt + dst)     = v0;
        *(f16x8_ma*)(vt + dst + 8) = v1;
    }
}

// -------- prep 3: W -> hi/lo bf16 planes TRANSPOSED, layout [e][d] --------
__global__ __launch_bounds__(256)
void transpose_split_w_kernel(const float* __restrict__ W,
                              unsigned short* __restrict__ wth,
                              unsigned short* __restrict__ wtl)
{
    __shared__ float t[64][68];
    const int tid = threadIdx.x;
    const int et  = blockIdx.x & 7;
    const int dt  = blockIdx.x >> 3;
    {
        const int rr = tid >> 4;
        const int c4 = (tid & 15) * 4;
        #pragma unroll
        for (int m4 = 0; m4 < 4; ++m4){
            const int dr = rr + m4*16;
            *(f32x4_ma*)&t[dr][c4] =
                *(const f32x4_ma*)&W[(size_t)(dt*64 + dr)*ND + et*64 + c4];
        }
    }
    __syncthreads();
    {
        const int er = tid >> 2;
        const int dc = (tid & 3) * 16;
        unsigned short hh[16], ll[16];
        #pragma unroll
        for (int j = 0; j < 16; ++j){
            const float v = t[dc + j][er];
            const unsigned short h = f2bf(v);
            hh[j] = h;
            ll[j] = f2bf(v - bf2f(h));
        }
        u32x4 h0, h1, l0, l1;
        #pragma unroll
        for (int c = 0; c < 4; ++c){
            h0[c] = (unsigned)hh[2*c]   | ((unsigned)hh[2*c+1] << 16);
            h1[c] = (unsigned)hh[8+2*c] | ((unsigned)hh[9+2*c] << 16);
            l0[c] = (unsigned)ll[2*c]   | ((unsigned)ll[2*c+1] << 16);
            l1[c] = (unsigned)ll[8+2*c] | ((unsigned)ll[9+2*c] << 16);
        }
        const size_t dst = (size_t)(et*64 + er)*ND + dt*64 + dc;
        *(u32x4_ma*)(wth + dst)     = h0;
        *(u32x4_ma*)(wth + dst + 8) = h1;
        *(u32x4_ma*)(wtl + dst)     = l0;
        *(u32x4_ma*)(wtl + dst + 8) = l1;
    }
}

// ----- main fused kernel: r14 structure (QB=64, KB=512) + register denominator -----
// (ones-MFMA deleted: -20% of MFMA work; denominator = same fp16 p, lane partials
//  rescaled by the same fsc sequence, reduced at epilogue -- r17-validated math)
__global__ __launch_bounds__(1024, 4)
void attn_kernel(const float* __restrict__ Qp, const int* __restrict__ Mp,
                 const _Float16* __restrict__ Kf,
                 const _Float16* __restrict__ Vt,
                 const unsigned short* __restrict__ Wth, const unsigned short* __restrict__ Wtl,
                 float* __restrict__ Op)
{
    __shared__ _Float16 qw[QB][520];    // 66.6 KB
    __shared__ _Float16 p_b[QB][520];   // 66.6 KB
    __shared__ float wredA[QB][16];     // 4 KB -> 137 KB total, 1 block/CU

    const int tid  = threadIdx.x;
    const int lane = tid & 63;
    const int wv   = tid >> 6;              // wave 0..15
    const int lm   = lane & 15;
    const int lg   = lane >> 4;
    const int b    = blockIdx.x & 7;        // batch -> XCD affinity
    const int q0   = (int)(blockIdx.x >> 3) * QB;

    int mk;
    {   // tolerate int64-encoded masks (values >=1, so odd words all-zero => int64)
        const int odd = Mp[1] | Mp[3] | Mp[5] | Mp[7];
        mk = (odd == 0) ? Mp[2*b] : Mp[b];
    }

    // ===== Phase 1: qw[64][512] = Q_tile @ W via bf16 hi/lo 3-term MFMA =====
    {
        f32x4 acc[4][2];
        #pragma unroll
        for (int m2 = 0; m2 < 4; ++m2)
            #pragma unroll
            for (int n2 = 0; n2 < 2; ++n2) acc[m2][n2] = (f32x4){0.f,0.f,0.f,0.f};

        for (int w = 0; w < 16; ++w){
            bf16x8 aH[4], aL[4];
            #pragma unroll
            for (int m2 = 0; m2 < 4; ++m2){
                const float* qp = Qp + ((size_t)b*NQ + q0 + m2*16 + lm)*ND + w*32 + lg*8;
                const f32x4 qa = *(const f32x4_ma*)qp;
                const f32x4 qb = *(const f32x4_ma*)(qp + 4);
                u16x8 hh, ll;
                #pragma unroll
                for (int c = 0; c < 4; ++c){
                    const unsigned short h = f2bf(qa[c]);
                    hh[c] = h; ll[c] = f2bf(qa[c] - bf2f(h));
                }
                #pragma unroll
                for (int c = 0; c < 4; ++c){
                    const unsigned short h = f2bf(qb[c]);
                    hh[4+c] = h; ll[4+c] = f2bf(qb[c] - bf2f(h));
                }
                aH[m2] = __builtin_bit_cast(bf16x8, hh);
                aL[m2] = __builtin_bit_cast(bf16x8, ll);
            }
            #pragma unroll
            for (int n2 = 0; n2 < 2; ++n2){
                const size_t wrow = (size_t)(wv*32 + n2*16 + lm)*ND + w*32 + lg*8;
                const bf16x8 bh = *(const bf16x8_ma*)(Wth + wrow);
                const bf16x8 bl = *(const bf16x8_ma*)(Wtl + wrow);
                #pragma unroll
                for (int m2 = 0; m2 < 4; ++m2){
                    acc[m2][n2] = __builtin_amdgcn_mfma_f32_16x16x32_bf16(aH[m2], bh, acc[m2][n2], 0,0,0);
                    acc[m2][n2] = __builtin_amdgcn_mfma_f32_16x16x32_bf16(aH[m2], bl, acc[m2][n2], 0,0,0);
                    acc[m2][n2] = __builtin_amdgcn_mfma_f32_16x16x32_bf16(aL[m2], bh, acc[m2][n2], 0,0,0);
                }
            }
        }
        #pragma unroll
        for (int m2 = 0; m2 < 4; ++m2)
            #pragma unroll
            for (int n2 = 0; n2 < 2; ++n2)
                #pragma unroll
                for (int r = 0; r < 4; ++r)
                    qw[m2*16 + lg*4 + r][wv*32 + n2*16 + lm] = (_Float16)acc[m2][n2][r];
    }
    __syncthreads();

    // ===== Phase 2: flash loop over 4 tiles of 512 keys =====
    float m_run[4][4], lsum[4][4];
    #pragma unroll
    for (int m2 = 0; m2 < 4; ++m2)
        #pragma unroll
        for (int r = 0; r < 4; ++r){ m_run[m2][r] = -3.0e38f; lsum[m2][r] = 0.f; }

    f32x4 o_acc[4][2];
    #pragma unroll
    for (int m2 = 0; m2 < 4; ++m2)
        #pragma unroll
        for (int n = 0; n < 2; ++n) o_acc[m2][n] = (f32x4){0.f,0.f,0.f,0.f};

    // wave owns keys {wv*16+lm, 256+wv*16+lm} within each 512-key tile
    const _Float16* kfb = Kf + ((size_t)b*NK + wv*16 + lm)*ND;
    const size_t vbase = ((size_t)b*ND + wv*32 + lm)*NK + lg*8;

    for (int kt = 0; kt < NK/KB; ++kt){
        const int k0 = kt * KB;
        const size_t koff = (size_t)k0 * ND;

        // ---- QK^T (fp16): same qw A-frags serve BOTH key halves ----
        f32x4 sacc[2][4];
        #pragma unroll
        for (int h = 0; h < 2; ++h)
            #pragma unroll
            for (int m2 = 0; m2 < 4; ++m2) sacc[h][m2] = (f32x4){0.f,0.f,0.f,0.f};
        #pragma unroll
        for (int w2 = 0; w2 < 8; ++w2){
            f16x8 bk[2][2];   // [j window][h half]
            #pragma unroll
            for (int j = 0; j < 2; ++j)
                #pragma unroll
                for (int h = 0; h < 2; ++h)
                    bk[j][h] = *(const f16x8_ma*)(kfb + koff + (size_t)h*256*ND + (w2*2 + j)*32 + lg*8);
            #pragma unroll
            for (int j = 0; j < 2; ++j){
                const int eoff = (w2*2 + j)*32 + lg*8;
                #pragma unroll
                for (int m2 = 0; m2 < 4; ++m2){
                    const f16x8 aQ = *(const f16x8_ma*)&qw[m2*16 + lm][eoff];
                    sacc[0][m2] = __builtin_amdgcn_mfma_f32_16x16x32_f16(aQ, bk[j][0], sacc[0][m2], 0,0,0);
                    sacc[1][m2] = __builtin_amdgcn_mfma_f32_16x16x32_f16(aQ, bk[j][1], sacc[1][m2], 0,0,0);
                }
            }
        }

        // ---- faithful mask (lane-local keys: k0 + h*256 + wv*16 + lm) ----
        float sv[2][4][4];
        #pragma unroll
        for (int h = 0; h < 2; ++h){
            const bool inval = (k0 + h*256 + wv*16 + lm) >= mk;
            #pragma unroll
            for (int m2 = 0; m2 < 4; ++m2)
                #pragma unroll
                for (int r = 0; r < 4; ++r)
                    sv[h][m2][r] = inval ? MASK_VALUE : sacc[h][m2][r];
        }

        // ---- per-wave row max over its 32 keys, publish ----
        float pm[4][4];
        #pragma unroll
        for (int m2 = 0; m2 < 4; ++m2)
            #pragma unroll
            for (int r = 0; r < 4; ++r) pm[m2][r] = fmaxf(sv[0][m2][r], sv[1][m2][r]);
        #pragma unroll
        for (int off = 1; off < 16; off <<= 1)
            #pragma unroll
            for (int m2 = 0; m2 < 4; ++m2)
                #pragma unroll
                for (int r = 0; r < 4; ++r)
                    pm[m2][r] = fmaxf(pm[m2][r], __shfl_xor(pm[m2][r], off, 64));
        if (lm == 0){
            #pragma unroll
            for (int m2 = 0; m2 < 4; ++m2)
                #pragma unroll
                for (int r = 0; r < 4; ++r) wredA[m2*16 + lg*4 + r][wv] = pm[m2][r];
        }
        __syncthreads();

        // ---- mnew + exact defer-max rescale + p -> fp16 LDS + register denominator ----
        #pragma unroll
        for (int m2 = 0; m2 < 4; ++m2)
            #pragma unroll
            for (int r = 0; r < 4; ++r){
                const int row = m2*16 + lg*4 + r;
                const f32x4 g0 = *(const f32x4_ma*)&wredA[row][0];
                const f32x4 g1 = *(const f32x4_ma*)&wredA[row][4];
                const f32x4 g2 = *(const f32x4_ma*)&wredA[row][8];
                const f32x4 g3 = *(const f32x4_ma*)&wredA[row][12];
                float gm = fmaxf(fmaxf(fmaxf(g0[0],g0[1]),fmaxf(g0[2],g0[3])),
                                 fmaxf(fmaxf(g1[0],g1[1]),fmaxf(g1[2],g1[3])));
                gm = fmaxf(gm, fmaxf(fmaxf(fmaxf(g2[0],g2[1]),fmaxf(g2[2],g2[3])),
                                     fmaxf(fmaxf(g3[0],g3[1]),fmaxf(g3[2],g3[3]))));
                if (gm > m_run[m2][r]){          // exact skip: fsc==1 when gm<=m_run
                    const float fsc = __expf(m_run[m2][r] - gm);
                    m_run[m2][r] = gm;
                    o_acc[m2][0][r] *= fsc;
                    o_acc[m2][1][r] *= fsc;
                    lsum[m2][r]     *= fsc;
                }
                const _Float16 ph0 = (_Float16)__expf(sv[0][m2][r] - m_run[m2][r]);
                const _Float16 ph1 = (_Float16)__expf(sv[1][m2][r] - m_run[m2][r]);
                p_b[row][wv*16 + lm]       = ph0;
                p_b[row][256 + wv*16 + lm] = ph1;
                lsum[m2][r] += (float)ph0 + (float)ph1;   // same fp16 p as PV numerator
            }
        __syncthreads();

        // ---- PV over 16 key-blocks of 32 (no ones-MFMA) ----
        #pragma unroll
        for (int kb = 0; kb < 16; ++kb){
            f16x8 pa[4];
            #pragma unroll
            for (int m2 = 0; m2 < 4; ++m2)
                pa[m2] = *(const f16x8_ma*)&p_b[m2*16 + lm][kb*32 + lg*8];
            #pragma unroll
            for (int n = 0; n < 2; ++n){
                const f16x8 vv = *(const f16x8_ma*)(Vt + vbase + (size_t)n*16*NK + k0 + kb*32);
                #pragma unroll
                for (int m2 = 0; m2 < 4; ++m2)
                    o_acc[m2][n] = __builtin_amdgcn_mfma_f32_16x16x32_f16(pa[m2], vv, o_acc[m2][n], 0,0,0);
            }
        }
    }

    // ===== epilogue: cross-lane + cross-wave denominator, normalize, store =====
    #pragma unroll
    for (int off = 1; off < 16; off <<= 1)
        #pragma unroll
        for (int m2 = 0; m2 < 4; ++m2)
            #pragma unroll
            for (int r = 0; r < 4; ++r)
                lsum[m2][r] += __shfl_xor(lsum[m2][r], off, 64);
    if (lm == 0){
        #pragma unroll
        for (int m2 = 0; m2 < 4; ++m2)
            #pragma unroll
            for (int r = 0; r < 4; ++r)
                wredA[m2*16 + lg*4 + r][wv] = lsum[m2][r];
    }
    __syncthreads();
    #pragma unroll
    for (int m2 = 0; m2 < 4; ++m2){
        float li[4];
        #pragma unroll
        for (int r = 0; r < 4; ++r){
            const int row = m2*16 + lg*4 + r;
            const f32x4 s0 = *(const f32x4_ma*)&wredA[row][0];
            const f32x4 s1 = *(const f32x4_ma*)&wredA[row][4];
            const f32x4 s2 = *(const f32x4_ma*)&wredA[row][8];
            const f32x4 s3 = *(const f32x4_ma*)&wredA[row][12];
            const float l = (((s0[0]+s0[1]) + (s0[2]+s0[3])) + ((s1[0]+s1[1]) + (s1[2]+s1[3])))
                          + (((s2[0]+s2[1]) + (s2[2]+s2[3])) + ((s3[0]+s3[1]) + (s3[2]+s3[3])));
            li[r] = 1.f / l;
        }
        #pragma unroll
        for (int n = 0; n < 2; ++n)
            #pragma unroll
            for (int r = 0; r < 4; ++r)
                Op[((size_t)b*NQ + q0 + m2*16 + lg*4 + r)*ND + wv*32 + n*16 + lm]
                    = o_acc[m2][n][r] * li[r];
    }
}

extern "C" void kernel_launch(void* const* d_in, const int* in_sizes, int n_in,
                              void* d_out, int out_size, void* d_ws, size_t ws_size,
                              hipStream_t stream)
{
    (void)in_sizes; (void)n_in; (void)out_size; (void)ws_size;
    const float* Qp = (const float*)d_in[0];
    const float* Kp = (const float*)d_in[1];
    const float* Vp = (const float*)d_in[2];
    const float* Wp = (const float*)d_in[3];
    const int*   Mp = (const int*)  d_in[4];
    float* Op = (float*)d_out;

    unsigned short* wsu = (unsigned short*)d_ws;   // 34.6 MB total
    _Float16*       Kf  = (_Float16*)wsu;
    _Float16*       Vt  = (_Float16*)(wsu + PLANE);
    unsigned short* Wth = wsu + 2*PLANE;
    unsigned short* Wtl = wsu + 2*PLANE + WPLANE;

    hipLaunchKernelGGL(conv_k_f16_kernel, dim3(PLANE/1024), dim3(256), 0, stream,
                       Kp, Kf);
    hipLaunchKernelGGL(transpose_v_f16_kernel, dim3(NB*32*8), dim3(256), 0, stream,
                       Vp, Vt);
    hipLaunchKernelGGL(transpose_split_w_kernel, dim3(64), dim3(256), 0, stream,
                       Wp, Wth, Wtl);
    hipLaunchKernelGGL(attn_kernel, dim3(NB*(NQ/QB)), dim3(1024), 0, stream,
                       Qp, Mp, Kf, Vt, Wth, Wtl, Op);
}